// Round 8
// baseline (1296.934 us; speedup 1.0000x reference)
//
#include <hip/hip_runtime.h>
#include <hip/hip_bf16.h>

// B=2, T=4 -> 8 clouds/side, N=16384 pts. Pads contribute 0 to sum and count,
// so only real points are processed (pad-key distances ~3e6 never win the min).
#define NPTS   16384
#define NCLOUD 16
#define NJOBS  16
#define BLK    256

// ---- 32x32x16 MFMA pass geometry ----
#define NA      2                     // A fragments per wave -> 64 queries/wave
#define QPW     (NA * 32)             // 64
#define QPB     (QPW * 4)             // 256 queries per block (4 waves)
#define QBLOCKS (NPTS / QPB)          // 64
#define KSPLIT  2
#define KPB     (NPTS / KSPLIT)       // 8192 keys per block
#define STAGE_KEYS 256
#define STAGE_U4   (STAGE_KEYS * 2)   // 512 uint4 = 8 KiB per stage buffer
#define NSTAGES    (KPB / STAGE_KEYS) // 32
#define CPS        (STAGE_KEYS / 32)  // 8 chunks (32 keys each) per stage
#define GRID1      (NJOBS * QBLOCKS * KSPLIT)   // 2048 = 8 XCD x 256

typedef __attribute__((ext_vector_type(8)))  short short8;
typedef __attribute__((ext_vector_type(16))) float f32x16;

__device__ __forceinline__ unsigned short f2bf(float x) {   // RNE f32->bf16
    unsigned u = __float_as_uint(x);
    u += 0x7fffu + ((u >> 16) & 1u);
    return (unsigned short)(u >> 16);
}
__device__ __forceinline__ float bf2f(unsigned short h) {
    return __uint_as_float(((unsigned)h) << 16);
}

// async global->LDS, 16B per lane; LDS dest is wave-uniform base (+ lane*16 by HW)
__device__ __forceinline__ void glds16(const uint4* g, uint4* l) {
    __builtin_amdgcn_global_load_lds(
        (const __attribute__((address_space(1))) void*)g,
        (__attribute__((address_space(3))) void*)l, 16, 0, 0);
}

// Pack each key into two 16B B-fragment records (bf16 split kh+kl, k2 3-way):
//   rec0 (K-slots 0-7):  [khx,khy,khz,khx,khy,khz,klx,kly]   for lanes < 32
//   rec1 (K-slots 8-15): [klz,klx,kly,klz,k2a,k2b,k2c,0]     for lanes >= 32
// Per cloud: 512 chunks of 32 keys; chunk = [32 x rec0][32 x rec1] = 1 KiB.
__global__ __launch_bounds__(BLK)
void cham_pack(const float* __restrict__ op, const float* __restrict__ tp,
               uint4* __restrict__ pk2) {
    const int gkey = blockIdx.x * BLK + threadIdx.x;     // 0 .. NCLOUD*NPTS-1
    const int c = gkey >> 14;
    const int i = gkey & (NPTS - 1);
    const float* src = (c < 8) ? (op + (size_t)c * NPTS * 3)
                               : (tp + (size_t)(c - 8) * NPTS * 3);
    const float x = src[i * 3 + 0];
    const float y = src[i * 3 + 1];
    const float z = src[i * 3 + 2];
    const unsigned khx = f2bf(x), khy = f2bf(y), khz = f2bf(z);
    const unsigned klx = f2bf(x - bf2f(khx));
    const unsigned kly = f2bf(y - bf2f(khy));
    const unsigned klz = f2bf(z - bf2f(khz));
    const float k2 = fmaf(x, x, fmaf(y, y, z * z));
    const unsigned k2a = f2bf(k2);
    float rres = k2 - bf2f(k2a);
    const unsigned k2b = f2bf(rres);
    rres -= bf2f(k2b);
    const unsigned k2c = f2bf(rres);

    uint4 r0, r1;
    r0.x = khx | (khy << 16); r0.y = khz | (khx << 16);
    r0.z = khy | (khz << 16); r0.w = klx | (kly << 16);
    r1.x = klz | (klx << 16); r1.y = kly | (klz << 16);
    r1.z = k2a | (k2b << 16); r1.w = k2c;

    const int chunk = i >> 5, slot = i & 31;
    const size_t base = (size_t)c * 32768 + (size_t)chunk * 64 + slot; // uint4 units
    pk2[base]      = r0;
    pk2[base + 32] = r1;
}

// A-fragment (32x32x16: row = lane&31, K-group g = lane>>5, k = g*8+j):
//   g0: [sxh,syh,szh,sxl,syl,szl,sxh,syh]   g1: [szh,sxl,syl,szl,1,1,1,0]
// with s = -2*q split into bf16 hi/lo.  acc = k2 - 2 q.k  (q2 added in pass2).
__global__ __launch_bounds__(BLK, 4)
void cham_mfma(const float* __restrict__ op, const float* __restrict__ tp,
               const uint4* __restrict__ pk2,
               float* __restrict__ w0, float* __restrict__ w1) {
    __shared__ uint4 smem[2][STAGE_U4];   // 2 x 8 KiB double buffer

    // XCD-bijective swizzle: 2048 = 8 x 256. HW round-robins bid%8 across
    // XCDs; remap so each XCD owns 256 consecutive work-ids (= 2 jobs) ->
    // that XCD's key stream stays in its private L2.
    const int wid  = ((blockIdx.x & 7) << 8) | (blockIdx.x >> 3);
    const int job  = wid >> 7;               // 128 blocks/job = 64 qblk x 2 ks
    const int rem  = wid & 127;
    const int qblk = rem >> 1;
    const int ks   = rem & 1;
    const int bt   = job >> 1, dir = job & 1;
    const float* qp = (dir == 0) ? (op + (size_t)bt * NPTS * 3)
                                 : (tp + (size_t)bt * NPTS * 3);
    const int kcloud = (dir == 0) ? (8 + bt) : bt;

    const int tid  = threadIdx.x;
    const int lane = tid & 63, w = tid >> 6;
    const int col  = lane & 31, g = lane >> 5;

    short8 a[NA];
    f32x16 m[NA];
    const unsigned short ONE = 0x3f80;   // bf16 1.0
    #pragma unroll
    for (int f = 0; f < NA; ++f) {
        const int qi = qblk * QPB + w * QPW + f * 32 + col;
        const float x = qp[qi * 3 + 0];
        const float y = qp[qi * 3 + 1];
        const float z = qp[qi * 3 + 2];
        const float sx = -2.0f * x, sy = -2.0f * y, sz = -2.0f * z;
        const unsigned short sxh = f2bf(sx), syh = f2bf(sy), szh = f2bf(sz);
        const unsigned short sxl = f2bf(sx - bf2f(sxh));
        const unsigned short syl = f2bf(sy - bf2f(syh));
        const unsigned short szl = f2bf(sz - bf2f(szh));
        if (g == 0) {
            a[f] = short8{(short)sxh, (short)syh, (short)szh, (short)sxl,
                          (short)syl, (short)szl, (short)sxh, (short)syh};
        } else {
            a[f] = short8{(short)szh, (short)sxl, (short)syl, (short)szl,
                          (short)ONE, (short)ONE, (short)ONE, (short)0};
        }
        #pragma unroll
        for (int r = 0; r < 16; ++r) m[f][r] = 3.0e38f;
    }

    const uint4* kbase = pk2 + (size_t)kcloud * 32768 + (size_t)ks * (KPB * 2);
    const f32x16 zero = {0.0f, 0.0f, 0.0f, 0.0f, 0.0f, 0.0f, 0.0f, 0.0f,
                         0.0f, 0.0f, 0.0f, 0.0f, 0.0f, 0.0f, 0.0f, 0.0f};

    // prologue: async-stage stage 0 into buf 0
    #pragma unroll
    for (int i = 0; i < STAGE_U4 / BLK; ++i)
        glds16(kbase + i * 256 + w * 64 + lane, &smem[0][i * 256 + w * 64]);
    __syncthreads();

    int cur = 0;
    for (int s = 0; s < NSTAGES; ++s) {
        // issue next stage's async loads into the other buffer; they stay in
        // flight across this stage's entire compute phase
        if (s + 1 < NSTAGES) {
            const uint4* gs = kbase + (size_t)(s + 1) * STAGE_U4;
            #pragma unroll
            for (int i = 0; i < STAGE_U4 / BLK; ++i)
                glds16(gs + i * 256 + w * 64 + lane, &smem[cur ^ 1][i * 256 + w * 64]);
        }

        #pragma unroll
        for (int cp = 0; cp < CPS / 2; ++cp) {
            const short8 b0 = *(const short8*)&smem[cur][cp * 128 + lane];
            const short8 b1 = *(const short8*)&smem[cur][cp * 128 + 64 + lane];
            #pragma unroll
            for (int f = 0; f < NA; ++f) {
                const f32x16 accA = __builtin_amdgcn_mfma_f32_32x32x16_bf16(a[f], b0, zero, 0, 0, 0);
                const f32x16 accB = __builtin_amdgcn_mfma_f32_32x32x16_bf16(a[f], b1, zero, 0, 0, 0);
                #pragma unroll
                for (int q = 0; q < 16; ++q)
                    m[f][q] = fminf(fminf(m[f][q], accA[q]), accB[q]);   // v_min3_f32
            }
        }

        __syncthreads();   // drains vmcnt (next buf ready) + closes this buf's readers
        cur ^= 1;
    }

    // D layout: col = lane&31 (key), row = (q&3) + 8*(q>>2) + 4*g (query).
    // Min over the 32 cols = butterfly over lane bits 0-4; rows don't mix.
    float* wj = ((ks == 0) ? w0 : w1) + job * NPTS + qblk * QPB + w * QPW;
    #pragma unroll
    for (int f = 0; f < NA; ++f) {
        #pragma unroll
        for (int q = 0; q < 16; ++q) {
            float v = m[f][q];
            v = fminf(v, __shfl_xor(v, 1, 64));
            v = fminf(v, __shfl_xor(v, 2, 64));
            v = fminf(v, __shfl_xor(v, 4, 64));
            v = fminf(v, __shfl_xor(v, 8, 64));
            v = fminf(v, __shfl_xor(v, 16, 64));
            if (col == 0)
                wj[f * 32 + (q & 3) + 8 * (q >> 2) + 4 * g] = v;   // plain store
        }
    }
}

// ---- fallback (ws too small for the pack): slow but correct, no atomics ----
__global__ __launch_bounds__(BLK)
void cham_fb(const float* __restrict__ op, const float* __restrict__ tp,
             float* __restrict__ w0, float* __restrict__ w1) {
    const int job = blockIdx.x >> 6;
    const int qb  = blockIdx.x & 63;
    const int bt  = job >> 1, dir = job & 1;
    const float* qp = (dir == 0) ? (op + (size_t)bt * NPTS * 3)
                                 : (tp + (size_t)bt * NPTS * 3);
    const float* kp = (dir == 0) ? (tp + (size_t)bt * NPTS * 3)
                                 : (op + (size_t)bt * NPTS * 3);
    const int qi = qb * BLK + threadIdx.x;
    const float x = qp[qi * 3], y = qp[qi * 3 + 1], z = qp[qi * 3 + 2];
    const float sx = -2.0f * x, sy = -2.0f * y, sz = -2.0f * z;
    float mv = 3.0e38f;
    for (int j = 0; j < NPTS; ++j) {
        const float kx = kp[j * 3], ky = kp[j * 3 + 1], kz = kp[j * 3 + 2];
        const float kw = fmaf(kx, kx, fmaf(ky, ky, kz * kz));
        mv = fminf(mv, fmaf(sx, kx, fmaf(sy, ky, fmaf(sz, kz, kw))));
    }
    w0[job * NPTS + qi] = mv;
    w1[job * NPTS + qi] = mv;
}

// one 1024-thread block per job: S = sum(max(q2+min(w0,w1),0)), P = count(>0)
#define BLK2 1024
__global__ __launch_bounds__(BLK2)
void cham_pass2(const float* __restrict__ op, const float* __restrict__ tp,
                const float* __restrict__ w0, const float* __restrict__ w1,
                float* __restrict__ ws2) {
    const int job = blockIdx.x;
    const int bt  = job >> 1, dir = job & 1;
    const float* qp = (dir == 0) ? (op + (size_t)bt * NPTS * 3)
                                 : (tp + (size_t)bt * NPTS * 3);
    const int tid = threadIdx.x;
    float S = 0.0f, P = 0.0f;
    for (int i = tid; i < NPTS; i += BLK2) {
        const float x = qp[i * 3], y = qp[i * 3 + 1], z = qp[i * 3 + 2];
        const float q2 = fmaf(x, x, fmaf(y, y, z * z));
        const float mv = fminf(w0[job * NPTS + i], w1[job * NPTS + i]);
        const float d = fmaxf(q2 + mv, 0.0f);
        S += d;
        P += (d > 0.0f) ? 1.0f : 0.0f;
    }
    #pragma unroll
    for (int o = 32; o > 0; o >>= 1) {
        S += __shfl_down(S, o, 64);
        P += __shfl_down(P, o, 64);
    }
    __shared__ float sS[16], sP[16];
    const int wv = tid >> 6;
    if ((tid & 63) == 0) { sS[wv] = S; sP[wv] = P; }
    __syncthreads();
    if (tid == 0) {
        float s = 0.0f, p = 0.0f;
        #pragma unroll
        for (int i = 0; i < 16; ++i) { s += sS[i]; p += sP[i]; }
        ws2[job * 2 + 0] = s;
        ws2[job * 2 + 1] = p;
    }
}

__global__ void cham_pass3(const float* __restrict__ ws2, float* __restrict__ out) {
    __shared__ float dc[8];
    const int t = threadIdx.x;
    if (t < 8) {
        const float s0 = ws2[(t * 2 + 0) * 2 + 0];
        const float p0 = ws2[(t * 2 + 0) * 2 + 1];
        const float s1 = ws2[(t * 2 + 1) * 2 + 0];
        const float p1 = ws2[(t * 2 + 1) * 2 + 1];
        dc[t] = s0 / p0 + s1 / p1;
    }
    __syncthreads();
    if (t < 8) out[4 + t] = dc[t];                           // tensor (T,B) row-major
    if (t < 4) out[t] = 0.5f * (dc[2 * t] + dc[2 * t + 1]);  // per-step mean
}

extern "C" void kernel_launch(void* const* d_in, const int* in_sizes, int n_in,
                              void* d_out, int out_size, void* d_ws, size_t ws_size,
                              hipStream_t stream) {
    const float* op = (const float*)d_in[0];
    const float* tp = (const float*)d_in[1];

    const size_t half_bytes = (size_t)NJOBS * NPTS * sizeof(float);   // 1 MiB each
    const size_t w1_off  = half_bytes;
    const size_t ws2_off = 2 * half_bytes;
    const size_t pk_off  = ws2_off + 256;
    const size_t pk_bytes = (size_t)NCLOUD * 32768 * sizeof(uint4);   // 8 MiB

    float* w0  = (float*)d_ws;
    float* w1  = (float*)((char*)d_ws + w1_off);
    float* ws2 = (float*)((char*)d_ws + ws2_off);
    uint4* pk2 = (uint4*)((char*)d_ws + pk_off);
    float* out = (float*)d_out;

    if (ws_size >= pk_off + pk_bytes) {
        // every w0/w1 slot written exactly once by a plain store: no memsets,
        // no atomics anywhere in the hot path.
        cham_pack<<<NCLOUD * NPTS / BLK, BLK, 0, stream>>>(op, tp, pk2);
        cham_mfma<<<GRID1, BLK, 0, stream>>>(op, tp, pk2, w0, w1);
    } else {
        cham_fb<<<NJOBS * 64, BLK, 0, stream>>>(op, tp, w0, w1);
    }
    cham_pass2<<<NJOBS, BLK2, 0, stream>>>(op, tp, w0, w1, ws2);
    cham_pass3<<<1, 64, 0, stream>>>(ws2, out);
}

// Round 9
// 258.440 us; speedup vs baseline: 5.0183x; 5.0183x over previous
//
#include <hip/hip_runtime.h>
#include <hip/hip_bf16.h>

// B=2, T=4 -> 8 clouds/side, N=16384 pts. Pads contribute 0 to sum and count,
// so only real points are processed (pad-key distances ~3e6 never win the min).
#define NPTS   16384
#define NCLOUD 16
#define NJOBS  16
#define BLK    256

// ---- 32x32x16 MFMA pass geometry ----
#define NA      2                     // A fragments per wave -> 64 queries/wave
#define QPW     (NA * 32)             // 64
#define QPB     (QPW * 4)             // 256 queries per block (4 waves)
#define QBLOCKS (NPTS / QPB)          // 64
#define KSPLIT  2
#define KPB     (NPTS / KSPLIT)       // 8192 keys per block
#define STAGE_KEYS 256
#define STAGE_U4   (STAGE_KEYS * 2)   // 512 uint4 = 8 KiB per stage buffer
#define NSTAGES    (KPB / STAGE_KEYS) // 32
#define CPS        (STAGE_KEYS / 32)  // 8 chunks (32 keys each) per stage
#define GRID1      (NJOBS * QBLOCKS * KSPLIT)   // 2048 = 8 XCD x 256

typedef __attribute__((ext_vector_type(8)))  short short8;
typedef __attribute__((ext_vector_type(16))) float f32x16;

__device__ __forceinline__ unsigned short f2bf(float x) {   // RNE f32->bf16
    unsigned u = __float_as_uint(x);
    u += 0x7fffu + ((u >> 16) & 1u);
    return (unsigned short)(u >> 16);
}
__device__ __forceinline__ float bf2f(unsigned short h) {
    return __uint_as_float(((unsigned)h) << 16);
}

// async global->LDS, 16B per lane; LDS dest is wave-uniform base (+ lane*16 by HW)
__device__ __forceinline__ void glds16(const uint4* g, uint4* l) {
    __builtin_amdgcn_global_load_lds(
        (const __attribute__((address_space(1))) void*)g,
        (__attribute__((address_space(3))) void*)l, 16, 0, 0);
}

// Pack each key into two 16B B-fragment records (bf16 split kh+kl, k2 3-way):
//   rec0 (K-slots 0-7):  [khx,khy,khz,khx,khy,khz,klx,kly]   for lanes < 32
//   rec1 (K-slots 8-15): [klz,klx,kly,klz,k2a,k2b,k2c,0]     for lanes >= 32
// Per cloud: 512 chunks of 32 keys; chunk = [32 x rec0][32 x rec1] = 1 KiB.
__global__ __launch_bounds__(BLK)
void cham_pack(const float* __restrict__ op, const float* __restrict__ tp,
               uint4* __restrict__ pk2) {
    const int gkey = blockIdx.x * BLK + threadIdx.x;     // 0 .. NCLOUD*NPTS-1
    const int c = gkey >> 14;
    const int i = gkey & (NPTS - 1);
    const float* src = (c < 8) ? (op + (size_t)c * NPTS * 3)
                               : (tp + (size_t)(c - 8) * NPTS * 3);
    const float x = src[i * 3 + 0];
    const float y = src[i * 3 + 1];
    const float z = src[i * 3 + 2];
    const unsigned khx = f2bf(x), khy = f2bf(y), khz = f2bf(z);
    const unsigned klx = f2bf(x - bf2f(khx));
    const unsigned kly = f2bf(y - bf2f(khy));
    const unsigned klz = f2bf(z - bf2f(khz));
    const float k2 = fmaf(x, x, fmaf(y, y, z * z));
    const unsigned k2a = f2bf(k2);
    float rres = k2 - bf2f(k2a);
    const unsigned k2b = f2bf(rres);
    rres -= bf2f(k2b);
    const unsigned k2c = f2bf(rres);

    uint4 r0, r1;
    r0.x = khx | (khy << 16); r0.y = khz | (khx << 16);
    r0.z = khy | (khz << 16); r0.w = klx | (kly << 16);
    r1.x = klz | (klx << 16); r1.y = kly | (klz << 16);
    r1.z = k2a | (k2b << 16); r1.w = k2c;

    const int chunk = i >> 5, slot = i & 31;
    const size_t base = (size_t)c * 32768 + (size_t)chunk * 64 + slot; // uint4 units
    pk2[base]      = r0;
    pk2[base + 32] = r1;
}

// A-fragment (32x32x16: row = lane&31, K-group g = lane>>5, k = g*8+j):
//   g0: [sxh,syh,szh,sxl,syl,szl,sxh,syh]   g1: [szh,sxl,syl,szl,1,1,1,0]
// with s = -2*q split into bf16 hi/lo.  acc = k2 - 2 q.k  (q2 added in pass2).
// NOTE: __launch_bounds__(BLK, 2): empirically (BLK,4) caps VGPR at 64 and
// spills ~2 GB of scratch per dispatch (R6, R8). (BLK,2) -> ~128 cap, no spill.
__global__ __launch_bounds__(BLK, 2)
void cham_mfma(const float* __restrict__ op, const float* __restrict__ tp,
               const uint4* __restrict__ pk2,
               float* __restrict__ w0, float* __restrict__ w1) {
    __shared__ uint4 smem[2][STAGE_U4];   // 2 x 8 KiB double buffer

    // XCD-bijective swizzle: 2048 = 8 x 256. HW round-robins bid%8 across
    // XCDs; remap so each XCD owns 256 consecutive work-ids (= 2 jobs) ->
    // that XCD's key stream (~1 MB) stays in its private L2.
    const int wid  = ((blockIdx.x & 7) << 8) | (blockIdx.x >> 3);
    const int job  = wid >> 7;               // 128 blocks/job = 64 qblk x 2 ks
    const int rem  = wid & 127;
    const int qblk = rem >> 1;
    const int ks   = rem & 1;
    const int bt   = job >> 1, dir = job & 1;
    const float* qp = (dir == 0) ? (op + (size_t)bt * NPTS * 3)
                                 : (tp + (size_t)bt * NPTS * 3);
    const int kcloud = (dir == 0) ? (8 + bt) : bt;

    const int tid  = threadIdx.x;
    const int lane = tid & 63, w = tid >> 6;
    const int col  = lane & 31, g = lane >> 5;

    short8 a[NA];
    f32x16 m[NA];
    const unsigned short ONE = 0x3f80;   // bf16 1.0
    #pragma unroll
    for (int f = 0; f < NA; ++f) {
        const int qi = qblk * QPB + w * QPW + f * 32 + col;
        const float x = qp[qi * 3 + 0];
        const float y = qp[qi * 3 + 1];
        const float z = qp[qi * 3 + 2];
        const float sx = -2.0f * x, sy = -2.0f * y, sz = -2.0f * z;
        const unsigned short sxh = f2bf(sx), syh = f2bf(sy), szh = f2bf(sz);
        const unsigned short sxl = f2bf(sx - bf2f(sxh));
        const unsigned short syl = f2bf(sy - bf2f(syh));
        const unsigned short szl = f2bf(sz - bf2f(szh));
        if (g == 0) {
            a[f] = short8{(short)sxh, (short)syh, (short)szh, (short)sxl,
                          (short)syl, (short)szl, (short)sxh, (short)syh};
        } else {
            a[f] = short8{(short)szh, (short)sxl, (short)syl, (short)szl,
                          (short)ONE, (short)ONE, (short)ONE, (short)0};
        }
        #pragma unroll
        for (int r = 0; r < 16; ++r) m[f][r] = 3.0e38f;
    }

    const uint4* kbase = pk2 + (size_t)kcloud * 32768 + (size_t)ks * (KPB * 2);
    const f32x16 zero = {0.0f, 0.0f, 0.0f, 0.0f, 0.0f, 0.0f, 0.0f, 0.0f,
                         0.0f, 0.0f, 0.0f, 0.0f, 0.0f, 0.0f, 0.0f, 0.0f};

    // prologue: async-stage stage 0 into buf 0
    #pragma unroll
    for (int i = 0; i < STAGE_U4 / BLK; ++i)
        glds16(kbase + i * 256 + w * 64 + lane, &smem[0][i * 256 + w * 64]);
    __syncthreads();

    int cur = 0;
    for (int s = 0; s < NSTAGES; ++s) {
        // issue next stage's async loads into the other buffer; they stay in
        // flight across this stage's entire compute phase
        if (s + 1 < NSTAGES) {
            const uint4* gs = kbase + (size_t)(s + 1) * STAGE_U4;
            #pragma unroll
            for (int i = 0; i < STAGE_U4 / BLK; ++i)
                glds16(gs + i * 256 + w * 64 + lane, &smem[cur ^ 1][i * 256 + w * 64]);
        }

        #pragma unroll
        for (int cp = 0; cp < CPS / 2; ++cp) {
            const short8 b0 = *(const short8*)&smem[cur][cp * 128 + lane];
            const short8 b1 = *(const short8*)&smem[cur][cp * 128 + 64 + lane];
            #pragma unroll
            for (int f = 0; f < NA; ++f) {
                const f32x16 accA = __builtin_amdgcn_mfma_f32_32x32x16_bf16(a[f], b0, zero, 0, 0, 0);
                const f32x16 accB = __builtin_amdgcn_mfma_f32_32x32x16_bf16(a[f], b1, zero, 0, 0, 0);
                #pragma unroll
                for (int q = 0; q < 16; ++q)
                    m[f][q] = fminf(fminf(m[f][q], accA[q]), accB[q]);   // v_min3_f32
            }
        }

        __syncthreads();   // drains vmcnt (next buf ready) + closes this buf's readers
        cur ^= 1;
    }

    // D layout: col = lane&31 (key), row = (q&3) + 8*(q>>2) + 4*g (query).
    // Min over the 32 cols = butterfly over lane bits 0-4; rows don't mix.
    float* wj = ((ks == 0) ? w0 : w1) + job * NPTS + qblk * QPB + w * QPW;
    #pragma unroll
    for (int f = 0; f < NA; ++f) {
        #pragma unroll
        for (int q = 0; q < 16; ++q) {
            float v = m[f][q];
            v = fminf(v, __shfl_xor(v, 1, 64));
            v = fminf(v, __shfl_xor(v, 2, 64));
            v = fminf(v, __shfl_xor(v, 4, 64));
            v = fminf(v, __shfl_xor(v, 8, 64));
            v = fminf(v, __shfl_xor(v, 16, 64));
            if (col == 0)
                wj[f * 32 + (q & 3) + 8 * (q >> 2) + 4 * g] = v;   // plain store
        }
    }
}

// ---- fallback (ws too small for the pack): slow but correct, no atomics ----
__global__ __launch_bounds__(BLK)
void cham_fb(const float* __restrict__ op, const float* __restrict__ tp,
             float* __restrict__ w0, float* __restrict__ w1) {
    const int job = blockIdx.x >> 6;
    const int qb  = blockIdx.x & 63;
    const int bt  = job >> 1, dir = job & 1;
    const float* qp = (dir == 0) ? (op + (size_t)bt * NPTS * 3)
                                 : (tp + (size_t)bt * NPTS * 3);
    const float* kp = (dir == 0) ? (tp + (size_t)bt * NPTS * 3)
                                 : (op + (size_t)bt * NPTS * 3);
    const int qi = qb * BLK + threadIdx.x;
    const float x = qp[qi * 3], y = qp[qi * 3 + 1], z = qp[qi * 3 + 2];
    const float sx = -2.0f * x, sy = -2.0f * y, sz = -2.0f * z;
    float mv = 3.0e38f;
    for (int j = 0; j < NPTS; ++j) {
        const float kx = kp[j * 3], ky = kp[j * 3 + 1], kz = kp[j * 3 + 2];
        const float kw = fmaf(kx, kx, fmaf(ky, ky, kz * kz));
        mv = fminf(mv, fmaf(sx, kx, fmaf(sy, ky, fmaf(sz, kz, kw))));
    }
    w0[job * NPTS + qi] = mv;
    w1[job * NPTS + qi] = mv;
}

// one 1024-thread block per job: S = sum(max(q2+min(w0,w1),0)), P = count(>0)
#define BLK2 1024
__global__ __launch_bounds__(BLK2)
void cham_pass2(const float* __restrict__ op, const float* __restrict__ tp,
                const float* __restrict__ w0, const float* __restrict__ w1,
                float* __restrict__ ws2) {
    const int job = blockIdx.x;
    const int bt  = job >> 1, dir = job & 1;
    const float* qp = (dir == 0) ? (op + (size_t)bt * NPTS * 3)
                                 : (tp + (size_t)bt * NPTS * 3);
    const int tid = threadIdx.x;
    float S = 0.0f, P = 0.0f;
    for (int i = tid; i < NPTS; i += BLK2) {
        const float x = qp[i * 3], y = qp[i * 3 + 1], z = qp[i * 3 + 2];
        const float q2 = fmaf(x, x, fmaf(y, y, z * z));
        const float mv = fminf(w0[job * NPTS + i], w1[job * NPTS + i]);
        const float d = fmaxf(q2 + mv, 0.0f);
        S += d;
        P += (d > 0.0f) ? 1.0f : 0.0f;
    }
    #pragma unroll
    for (int o = 32; o > 0; o >>= 1) {
        S += __shfl_down(S, o, 64);
        P += __shfl_down(P, o, 64);
    }
    __shared__ float sS[16], sP[16];
    const int wv = tid >> 6;
    if ((tid & 63) == 0) { sS[wv] = S; sP[wv] = P; }
    __syncthreads();
    if (tid == 0) {
        float s = 0.0f, p = 0.0f;
        #pragma unroll
        for (int i = 0; i < 16; ++i) { s += sS[i]; p += sP[i]; }
        ws2[job * 2 + 0] = s;
        ws2[job * 2 + 1] = p;
    }
}

__global__ void cham_pass3(const float* __restrict__ ws2, float* __restrict__ out) {
    __shared__ float dc[8];
    const int t = threadIdx.x;
    if (t < 8) {
        const float s0 = ws2[(t * 2 + 0) * 2 + 0];
        const float p0 = ws2[(t * 2 + 0) * 2 + 1];
        const float s1 = ws2[(t * 2 + 1) * 2 + 0];
        const float p1 = ws2[(t * 2 + 1) * 2 + 1];
        dc[t] = s0 / p0 + s1 / p1;
    }
    __syncthreads();
    if (t < 8) out[4 + t] = dc[t];                           // tensor (T,B) row-major
    if (t < 4) out[t] = 0.5f * (dc[2 * t] + dc[2 * t + 1]);  // per-step mean
}

extern "C" void kernel_launch(void* const* d_in, const int* in_sizes, int n_in,
                              void* d_out, int out_size, void* d_ws, size_t ws_size,
                              hipStream_t stream) {
    const float* op = (const float*)d_in[0];
    const float* tp = (const float*)d_in[1];

    const size_t half_bytes = (size_t)NJOBS * NPTS * sizeof(float);   // 1 MiB each
    const size_t w1_off  = half_bytes;
    const size_t ws2_off = 2 * half_bytes;
    const size_t pk_off  = ws2_off + 256;
    const size_t pk_bytes = (size_t)NCLOUD * 32768 * sizeof(uint4);   // 8 MiB

    float* w0  = (float*)d_ws;
    float* w1  = (float*)((char*)d_ws + w1_off);
    float* ws2 = (float*)((char*)d_ws + ws2_off);
    uint4* pk2 = (uint4*)((char*)d_ws + pk_off);
    float* out = (float*)d_out;

    if (ws_size >= pk_off + pk_bytes) {
        // every w0/w1 slot written exactly once by a plain store: no memsets,
        // no atomics anywhere in the hot path.
        cham_pack<<<NCLOUD * NPTS / BLK, BLK, 0, stream>>>(op, tp, pk2);
        cham_mfma<<<GRID1, BLK, 0, stream>>>(op, tp, pk2, w0, w1);
    } else {
        cham_fb<<<NJOBS * 64, BLK, 0, stream>>>(op, tp, w0, w1);
    }
    cham_pass2<<<NJOBS, BLK2, 0, stream>>>(op, tp, w0, w1, ws2);
    cham_pass3<<<1, 64, 0, stream>>>(ws2, out);
}

// Round 11
// 214.534 us; speedup vs baseline: 6.0454x; 1.2047x over previous
//
#include <hip/hip_runtime.h>
#include <hip/hip_bf16.h>

// B=2, T=4 -> 8 clouds/side, N=16384 pts. Pads contribute 0 to sum and count,
// so only real points are processed (pad-key distances ~3e6 never win the min).
#define NPTS   16384
#define NCLOUD 16
#define NJOBS  16
#define BLK    256

// ---- 32x32x16 MFMA pass geometry (hot loop == R7's measured no-spill loop) ----
#define NA      4                     // A fragments per wave -> 128 queries/wave
#define QPW     (NA * 32)             // 128
#define QPB     (QPW * 4)             // 512 queries per block (4 waves)
#define QBLOCKS (NPTS / QPB)          // 32
#define KSPLIT  4
#define KPB     (NPTS / KSPLIT)       // 4096 keys per block
#define STAGE_KEYS 512
#define STAGE_U4   (STAGE_KEYS * 2)   // 1024 uint4 = 16 KiB per stage buffer
#define NSTAGES    (KPB / STAGE_KEYS) // 8
#define CPS        (STAGE_KEYS / 32)  // 16 chunks (32 keys each) per stage
#define GRID1      (NJOBS * QBLOCKS * KSPLIT)   // 2048 = 8 XCD x 256

typedef __attribute__((ext_vector_type(8)))  short short8;
typedef __attribute__((ext_vector_type(16))) float f32x16;

__device__ __forceinline__ unsigned short f2bf(float x) {   // RNE f32->bf16
    unsigned u = __float_as_uint(x);
    u += 0x7fffu + ((u >> 16) & 1u);
    return (unsigned short)(u >> 16);
}
__device__ __forceinline__ float bf2f(unsigned short h) {
    return __uint_as_float(((unsigned)h) << 16);
}

// async global->LDS, 16B per lane; LDS dest is wave-uniform base (+ lane*16 by HW)
__device__ __forceinline__ void glds16(const uint4* g, uint4* l) {
    __builtin_amdgcn_global_load_lds(
        (const __attribute__((address_space(1))) void*)g,
        (__attribute__((address_space(3))) void*)l, 16, 0, 0);
}

// Pack each key into two 16B B-fragment records (bf16 split kh+kl, k2 3-way):
//   rec0 (K-slots 0-7):  [khx,khy,khz,khx,khy,khz,klx,kly]   for lanes < 32
//   rec1 (K-slots 8-15): [klz,klx,kly,klz,k2a,k2b,k2c,0]     for lanes >= 32
// Per cloud: 512 chunks of 32 keys; chunk = [32 x rec0][32 x rec1] = 1 KiB.
__global__ __launch_bounds__(BLK)
void cham_pack(const float* __restrict__ op, const float* __restrict__ tp,
               uint4* __restrict__ pk2) {
    const int gkey = blockIdx.x * BLK + threadIdx.x;     // 0 .. NCLOUD*NPTS-1
    const int c = gkey >> 14;
    const int i = gkey & (NPTS - 1);
    const float* src = (c < 8) ? (op + (size_t)c * NPTS * 3)
                               : (tp + (size_t)(c - 8) * NPTS * 3);
    const float x = src[i * 3 + 0];
    const float y = src[i * 3 + 1];
    const float z = src[i * 3 + 2];
    const unsigned khx = f2bf(x), khy = f2bf(y), khz = f2bf(z);
    const unsigned klx = f2bf(x - bf2f(khx));
    const unsigned kly = f2bf(y - bf2f(khy));
    const unsigned klz = f2bf(z - bf2f(khz));
    const float k2 = fmaf(x, x, fmaf(y, y, z * z));
    const unsigned k2a = f2bf(k2);
    float rres = k2 - bf2f(k2a);
    const unsigned k2b = f2bf(rres);
    rres -= bf2f(k2b);
    const unsigned k2c = f2bf(rres);

    uint4 r0, r1;
    r0.x = khx | (khy << 16); r0.y = khz | (khx << 16);
    r0.z = khy | (khz << 16); r0.w = klx | (kly << 16);
    r1.x = klz | (klx << 16); r1.y = kly | (klz << 16);
    r1.z = k2a | (k2b << 16); r1.w = k2c;

    const int chunk = i >> 5, slot = i & 31;
    const size_t base = (size_t)c * 32768 + (size_t)chunk * 64 + slot; // uint4 units
    pk2[base]      = r0;
    pk2[base + 32] = r1;
}

// A-fragment (32x32x16: row = lane&31, K-group g = lane>>5, k = g*8+j):
//   g0: [sxh,syh,szh,sxl,syl,szl,sxh,syh]   g1: [szh,sxl,syl,szl,1,1,1,0]
// with s = -2*q split into bf16 hi/lo.  acc = k2 - 2 q.k  (q2 added in pass2).
// NOTE (measured, R6/R8/R9): (BLK,4) or full inner unroll -> VGPR cap/pressure
// -> ~100 MB scratch spill. The no-spill envelope is exactly this loop:
// NA=4, unroll 2, launch_bounds(BLK,2) -> VGPR=100, WRITE_SIZE ~2 MB (R7).
__global__ __launch_bounds__(BLK, 2)
void cham_mfma(const float* __restrict__ op, const float* __restrict__ tp,
               const uint4* __restrict__ pk2, float* __restrict__ wk) {
    __shared__ uint4 smem[2][STAGE_U4];   // 2 x 16 KiB double buffer

    // XCD-bijective swizzle: 2048 = 8 x 256. HW round-robins bid%8 across
    // XCDs; remap so each XCD owns 256 consecutive work-ids (= 2 jobs) ->
    // that XCD's key stream (~1 MB packed) stays in its private L2.
    const int wid  = ((blockIdx.x & 7) << 8) | (blockIdx.x >> 3);
    const int job  = wid >> 7;               // 128 blocks/job = 32 qblk x 4 ks
    const int rem  = wid & 127;
    const int qblk = rem >> 2;
    const int ks   = rem & 3;
    const int bt   = job >> 1, dir = job & 1;
    const float* qp = (dir == 0) ? (op + (size_t)bt * NPTS * 3)
                                 : (tp + (size_t)bt * NPTS * 3);
    const int kcloud = (dir == 0) ? (8 + bt) : bt;

    const int tid  = threadIdx.x;
    const int lane = tid & 63, w = tid >> 6;
    const int col  = lane & 31, g = lane >> 5;

    short8 a[NA];
    f32x16 m[NA];
    const unsigned short ONE = 0x3f80;   // bf16 1.0
    #pragma unroll
    for (int f = 0; f < NA; ++f) {
        const int qi = qblk * QPB + w * QPW + f * 32 + col;
        const float x = qp[qi * 3 + 0];
        const float y = qp[qi * 3 + 1];
        const float z = qp[qi * 3 + 2];
        const float sx = -2.0f * x, sy = -2.0f * y, sz = -2.0f * z;
        const unsigned short sxh = f2bf(sx), syh = f2bf(sy), szh = f2bf(sz);
        const unsigned short sxl = f2bf(sx - bf2f(sxh));
        const unsigned short syl = f2bf(sy - bf2f(syh));
        const unsigned short szl = f2bf(sz - bf2f(szh));
        if (g == 0) {
            a[f] = short8{(short)sxh, (short)syh, (short)szh, (short)sxl,
                          (short)syl, (short)szl, (short)sxh, (short)syh};
        } else {
            a[f] = short8{(short)szh, (short)sxl, (short)syl, (short)szl,
                          (short)ONE, (short)ONE, (short)ONE, (short)0};
        }
        #pragma unroll
        for (int r = 0; r < 16; ++r) m[f][r] = 3.0e38f;
    }

    const uint4* kbase = pk2 + (size_t)kcloud * 32768 + (size_t)ks * (KPB * 2);
    const f32x16 zero = {0.0f, 0.0f, 0.0f, 0.0f, 0.0f, 0.0f, 0.0f, 0.0f,
                         0.0f, 0.0f, 0.0f, 0.0f, 0.0f, 0.0f, 0.0f, 0.0f};

    // prologue: async-stage stage 0 into buf 0
    #pragma unroll
    for (int i = 0; i < STAGE_U4 / BLK; ++i)
        glds16(kbase + i * 256 + w * 64 + lane, &smem[0][i * 256 + w * 64]);
    __syncthreads();

    int cur = 0;
    for (int s = 0; s < NSTAGES; ++s) {
        // issue next stage's async loads into the other buffer; they stay in
        // flight across this stage's entire compute phase
        if (s + 1 < NSTAGES) {
            const uint4* gs = kbase + (size_t)(s + 1) * STAGE_U4;
            #pragma unroll
            for (int i = 0; i < STAGE_U4 / BLK; ++i)
                glds16(gs + i * 256 + w * 64 + lane, &smem[cur ^ 1][i * 256 + w * 64]);
        }

        #pragma unroll 2
        for (int cp = 0; cp < CPS / 2; ++cp) {
            const short8 b0 = *(const short8*)&smem[cur][cp * 128 + lane];
            const short8 b1 = *(const short8*)&smem[cur][cp * 128 + 64 + lane];
            #pragma unroll
            for (int f = 0; f < NA; ++f) {
                const f32x16 accA = __builtin_amdgcn_mfma_f32_32x32x16_bf16(a[f], b0, zero, 0, 0, 0);
                const f32x16 accB = __builtin_amdgcn_mfma_f32_32x32x16_bf16(a[f], b1, zero, 0, 0, 0);
                #pragma unroll
                for (int q = 0; q < 16; ++q)
                    m[f][q] = fminf(fminf(m[f][q], accA[q]), accB[q]);   // v_min3_f32
            }
        }

        __syncthreads();   // drains vmcnt (next buf ready) + closes this buf's readers
        cur ^= 1;
    }

    // D layout: col = lane&31 (key), row = (q&3) + 8*(q>>2) + 4*g (query).
    // Min over the 32 cols = butterfly over lane bits 0-4; rows don't mix.
    float* wj = wk + (size_t)ks * (NJOBS * NPTS) + job * NPTS + qblk * QPB + w * QPW;
    #pragma unroll
    for (int f = 0; f < NA; ++f) {
        #pragma unroll
        for (int q = 0; q < 16; ++q) {
            float v = m[f][q];
            v = fminf(v, __shfl_xor(v, 1, 64));
            v = fminf(v, __shfl_xor(v, 2, 64));
            v = fminf(v, __shfl_xor(v, 4, 64));
            v = fminf(v, __shfl_xor(v, 8, 64));
            v = fminf(v, __shfl_xor(v, 16, 64));
            if (col == 0)
                wj[f * 32 + (q & 3) + 8 * (q >> 2) + 4 * g] = v;   // plain store
        }
    }
}

// ---- fallback (ws too small for the pack): slow but correct, no atomics ----
__global__ __launch_bounds__(BLK)
void cham_fb(const float* __restrict__ op, const float* __restrict__ tp,
             float* __restrict__ wk) {
    const int job = blockIdx.x >> 6;
    const int qb  = blockIdx.x & 63;
    const int bt  = job >> 1, dir = job & 1;
    const float* qp = (dir == 0) ? (op + (size_t)bt * NPTS * 3)
                                 : (tp + (size_t)bt * NPTS * 3);
    const float* kp = (dir == 0) ? (tp + (size_t)bt * NPTS * 3)
                                 : (op + (size_t)bt * NPTS * 3);
    const int qi = qb * BLK + threadIdx.x;
    const float x = qp[qi * 3], y = qp[qi * 3 + 1], z = qp[qi * 3 + 2];
    const float sx = -2.0f * x, sy = -2.0f * y, sz = -2.0f * z;
    float mv = 3.0e38f;
    for (int j = 0; j < NPTS; ++j) {
        const float kx = kp[j * 3], ky = kp[j * 3 + 1], kz = kp[j * 3 + 2];
        const float kw = fmaf(kx, kx, fmaf(ky, ky, kz * kz));
        mv = fminf(mv, fmaf(sx, kx, fmaf(sy, ky, fmaf(sz, kz, kw))));
    }
    #pragma unroll
    for (int kx = 0; kx < KSPLIT; ++kx)
        wk[(size_t)kx * (NJOBS * NPTS) + job * NPTS + qi] = mv;
}

// one 1024-thread block per job: S = sum(max(q2+min_k wk,0)), P = count(>0)
#define BLK2 1024
__global__ __launch_bounds__(BLK2)
void cham_pass2(const float* __restrict__ op, const float* __restrict__ tp,
                const float* __restrict__ wk, float* __restrict__ ws2) {
    const int job = blockIdx.x;
    const int bt  = job >> 1, dir = job & 1;
    const float* qp = (dir == 0) ? (op + (size_t)bt * NPTS * 3)
                                 : (tp + (size_t)bt * NPTS * 3);
    const int tid = threadIdx.x;
    const float* wj0 = wk + job * NPTS;
    const float* wj1 = wj0 + (size_t)1 * NJOBS * NPTS;
    const float* wj2 = wj0 + (size_t)2 * NJOBS * NPTS;
    const float* wj3 = wj0 + (size_t)3 * NJOBS * NPTS;
    float S = 0.0f, P = 0.0f;
    for (int i = tid; i < NPTS; i += BLK2) {
        const float x = qp[i * 3], y = qp[i * 3 + 1], z = qp[i * 3 + 2];
        const float q2 = fmaf(x, x, fmaf(y, y, z * z));
        const float mv = fminf(fminf(wj0[i], wj1[i]), fminf(wj2[i], wj3[i]));
        const float d = fmaxf(q2 + mv, 0.0f);
        S += d;
        P += (d > 0.0f) ? 1.0f : 0.0f;
    }
    #pragma unroll
    for (int o = 32; o > 0; o >>= 1) {
        S += __shfl_down(S, o, 64);
        P += __shfl_down(P, o, 64);
    }
    __shared__ float sS[16], sP[16];
    const int wv = tid >> 6;
    if ((tid & 63) == 0) { sS[wv] = S; sP[wv] = P; }
    __syncthreads();
    if (tid == 0) {
        float s = 0.0f, p = 0.0f;
        #pragma unroll
        for (int i = 0; i < 16; ++i) { s += sS[i]; p += sP[i]; }
        ws2[job * 2 + 0] = s;
        ws2[job * 2 + 1] = p;
    }
}

__global__ void cham_pass3(const float* __restrict__ ws2, float* __restrict__ out) {
    __shared__ float dc[8];
    const int t = threadIdx.x;
    if (t < 8) {
        const float s0 = ws2[(t * 2 + 0) * 2 + 0];
        const float p0 = ws2[(t * 2 + 0) * 2 + 1];
        const float s1 = ws2[(t * 2 + 1) * 2 + 0];
        const float p1 = ws2[(t * 2 + 1) * 2 + 1];
        dc[t] = s0 / p0 + s1 / p1;
    }
    __syncthreads();
    if (t < 8) out[4 + t] = dc[t];                           // tensor (T,B) row-major
    if (t < 4) out[t] = 0.5f * (dc[2 * t] + dc[2 * t + 1]);  // per-step mean
}

extern "C" void kernel_launch(void* const* d_in, const int* in_sizes, int n_in,
                              void* d_out, int out_size, void* d_ws, size_t ws_size,
                              hipStream_t stream) {
    const float* op = (const float*)d_in[0];
    const float* tp = (const float*)d_in[1];

    const size_t wk_bytes = (size_t)KSPLIT * NJOBS * NPTS * sizeof(float); // 4 MiB
    const size_t ws2_off  = wk_bytes;
    const size_t pk_off   = ws2_off + 256;
    const size_t pk_bytes = (size_t)NCLOUD * 32768 * sizeof(uint4);        // 8 MiB

    float* wk  = (float*)d_ws;
    float* ws2 = (float*)((char*)d_ws + ws2_off);
    uint4* pk2 = (uint4*)((char*)d_ws + pk_off);
    float* out = (float*)d_out;

    if (ws_size >= pk_off + pk_bytes) {
        // every wk slot written exactly once by a plain store: no memsets,
        // no atomics anywhere in the hot path.
        cham_pack<<<NCLOUD * NPTS / BLK, BLK, 0, stream>>>(op, tp, pk2);
        cham_mfma<<<GRID1, BLK, 0, stream>>>(op, tp, pk2, wk);
    } else {
        cham_fb<<<NJOBS * 64, BLK, 0, stream>>>(op, tp, wk);
    }
    cham_pass2<<<NJOBS, BLK2, 0, stream>>>(op, tp, wk, ws2);
    cham_pass3<<<1, 64, 0, stream>>>(ws2, out);
}